// Round 7
// baseline (206.442 us; speedup 1.0000x reference)
//
#include <hip/hip_runtime.h>

// Dilate = 5x5 per-channel max filter, SAME padding, (64,384,384,3) f32.
// v7 = v6 staging (global_load_lds ring + counted vmcnt + raw barriers,
//      machinery verified to execute) + v5 compute (strip/shuffle horizontal,
//      verified absmax 0.0 for 5 rounds).
//   v6 post-mortem: absmax 0.63 was MY formula bug — horizontal window
//   spans words c-2..c+2 (channel stride 3 => +-6 floats), v6 read only
//   c-1..c+1 and scrambled the element mapping. Staging/sync was sound:
//   each wave vm_waits its OWN stage loads, s_barrier collectivizes.
//   Structure:
//   - block = 320 thr (5 waves) owns a 24-row band of one image
//   - LDS ring of 8 full rows (36,864 B) staged via global_load_lds w=16
//     (1 instr/wave/row; waves 0-3: 1024 B, wave 4: lanes<32, 512 B)
//   - counted vmcnt (never 0 mid-loop): N(k) from per-wave FIFO
//     (1 stage + 1 store per round): k=0:3 1:4 2:5 3..20:6 21:5 22:4 23:3
//   - raw s_barrier (NOT __syncthreads - would drain vmcnt(0))
//   - compute: wave wv owns cols wv*60-2+lane; vert5 = 5x ds_read_b128 own
//     col; horizontal via 12 intra-wave shuffles (v5 formulas); store lanes
//     2..61. Vertical SAME padding via address clamp (dup row = identity).
//   grid = 64 img x 16 bands = 1024 blocks = exactly 4/CU (LDS: 4x36.9KB
//   = 147KB/CU), 20 waves/CU; XCD swizzle keeps each XCD on 8 images.

#define Bn 64
#define H 384
#define ROWB 4608            // bytes per image row (384*3*4)
#define WF4 288              // float4 words per row
#define RB 24                // output rows per block
#define NIN (RB + 4)         // 28 input rows incl halo
#define BANDS (H / RB)       // 16
#define NBLK (Bn * BANDS)    // 1024 (divisible by 8)
#define NTHR 320
#define NEGINF (-3.402823466e+38f)

typedef float f32x4 __attribute__((ext_vector_type(4)));

template <int I> struct Ic { static constexpr int v = I; };
template <int I, int N, class F>
__device__ __forceinline__ void static_for(F f) {
  if constexpr (I < N) {
    f(Ic<I>{});
    static_for<I + 1, N>(f);
  }
}

// Counted vmcnt wait, fenced both sides (rule #18).
template <int N>
__device__ __forceinline__ void vm_wait() {
  __builtin_amdgcn_sched_barrier(0);
  asm volatile("s_waitcnt vmcnt(%0)" ::"n"(N) : "memory");
  __builtin_amdgcn_sched_barrier(0);
}

// Per-wave FIFO wait count before consuming rows k..k+4 (derived entry-by-
// entry; stages s0..s6 prologue, round k<=20: {stage s(k+7), store st(k)}).
__host__ __device__ constexpr int NW(int k) {
  return k == 0 ? 3 : k == 1 ? 4 : k == 2 ? 5 : k <= 20 ? 6
       : k == 21 ? 5 : k == 22 ? 4 : 3;
}

__device__ __forceinline__ f32x4 max4(f32x4 a, f32x4 b) {
  f32x4 r;
  r.x = fmaxf(a.x, b.x); r.y = fmaxf(a.y, b.y);
  r.z = fmaxf(a.z, b.z); r.w = fmaxf(a.w, b.w);
  return r;
}

__global__ __launch_bounds__(NTHR, 5) void dilate5_kernel(
    const float* __restrict__ in, float* __restrict__ out) {
  __shared__ f32x4 ring[8][WF4];               // 8 x 4608 B = 36,864 B

  const int t = threadIdx.x;
  const int wv = t >> 6;
  const int lane = t & 63;

  // XCD swizzle: XCD x owns 8 consecutive images (verified FETCH win).
  const int orig = blockIdx.x;
  const int q = (orig & 7) * (NBLK / 8) + (orig >> 3);
  const int band = q % BANDS;
  const int b = q / BANDS;
  const int r0 = band * RB;

  const char* __restrict__ imgb = (const char*)in + (size_t)b * H * ROWB;
  char* __restrict__ outb = (char*)out + (size_t)b * H * ROWB;

  // ---- staging: every wave issues EXACTLY 1 global_load_lds per row ----
  const int soff = wv * 1024 + lane * 16;      // byte offset within a row
  const bool sact = soff < ROWB;               // wave 4: lanes 0..31 only
  char* lds0 = (char*)&ring[0][0];

  auto stage = [&](int j) {                    // input row index 0..NIN-1
    int gh = r0 - 2 + j;
    gh = gh < 0 ? 0 : (gh > H - 1 ? H - 1 : gh);   // vertical SAME padding
    const char* src = imgb + (size_t)gh * ROWB + soff;
    char* dst = lds0 + (size_t)(j & 7) * ROWB + soff;
    if (sact)
      __builtin_amdgcn_global_load_lds(
          (const __attribute__((address_space(1))) void*)src,
          (__attribute__((address_space(3))) void*)dst, 16, 0, 0);
  };

  // ---- compute geometry (v5-verified): wave wv owns 60-col strip with
  // +-2 lane halo; col may be OOB -> -inf via cvalid. ----
  const int col = wv * 60 - 2 + lane;
  const bool cvalid = (col >= 0) && (col < WF4);
  const int ccl = col < 0 ? 0 : (col > WF4 - 1 ? WF4 - 1 : col);
  const bool willstore = (lane >= 2) && (lane < 62) && (col < WF4);

  // ---- prologue: stage rows 0..6 ----
#pragma unroll
  for (int j = 0; j < 7; ++j) stage(j);

  // ---- 24 rounds: stage k+7 | vmcnt(NW(k)) | bar | compute k | bar ----
  static_for<0, RB>([&](auto ic) {
    constexpr int k = decltype(ic)::v;
    if constexpr (k <= 20) stage(k + 7);
    vm_wait<NW(k)>();
    __builtin_amdgcn_s_barrier();

    // vertical 5-max from LDS ring, own column (5x ds_read_b128)
    f32x4 v = max4(max4(max4(ring[(k + 0) & 7][ccl], ring[(k + 1) & 7][ccl]),
                        max4(ring[(k + 2) & 7][ccl], ring[(k + 3) & 7][ccl])),
                   ring[(k + 4) & 7][ccl]);
    if (!cvalid) { v.x = NEGINF; v.y = NEGINF; v.z = NEGINF; v.w = NEGINF; }

    // horizontal 5-max, channel stride 3 (v5-verified formulas):
    // word c-2 contributes only .z/.w, word c+2 only .x/.y -> 12 shuffles.
    float Bx = __shfl_up(v.x, 1), By = __shfl_up(v.y, 1);
    float Bz = __shfl_up(v.z, 1), Bw = __shfl_up(v.w, 1);
    float Dx = __shfl_down(v.x, 1), Dy = __shfl_down(v.y, 1);
    float Dz = __shfl_down(v.z, 1), Dw = __shfl_down(v.w, 1);
    float Az = __shfl_up(v.z, 2), Aw = __shfl_up(v.w, 2);
    float Ex = __shfl_down(v.x, 2), Ey = __shfl_down(v.y, 2);
    f32x4 h;
    h.x = fmaxf(fmaxf(fmaxf(Az, By), fmaxf(v.x, v.w)), Dz);
    h.y = fmaxf(fmaxf(fmaxf(Aw, Bz), fmaxf(v.y, Dx)), Dw);
    h.z = fmaxf(fmaxf(fmaxf(Bx, Bw), fmaxf(v.z, Dy)), Ex);
    h.w = fmaxf(fmaxf(fmaxf(By, v.x), fmaxf(v.w, Dz)), Ey);

    if (willstore)
      *reinterpret_cast<f32x4*>(outb + (size_t)(r0 + k) * ROWB +
                                (size_t)col * 16) = h;

    __builtin_amdgcn_s_barrier();   // slot (k)&7 reused by stage(k+8)
  });
}

extern "C" void kernel_launch(void* const* d_in, const int* in_sizes, int n_in,
                              void* d_out, int out_size, void* d_ws, size_t ws_size,
                              hipStream_t stream) {
  const float* images = (const float*)d_in[0];
  float* out = (float*)d_out;
  dilate5_kernel<<<NBLK, NTHR, 0, stream>>>(images, out);
}